// Round 12
// baseline (1540.458 us; speedup 1.0000x reference)
//
#include <hip/hip_runtime.h>
#include <cstdint>

#define NN 50000
#define NE 800000

typedef __attribute__((ext_vector_type(8))) short    s16x8;
typedef __attribute__((ext_vector_type(4))) float    f32x4;
typedef __attribute__((ext_vector_type(4))) unsigned short u16x4;
typedef _Float16 f16x8 __attribute__((ext_vector_type(8)));

typedef unsigned short ushort_t;
typedef unsigned int   uint_t;

__device__ __forceinline__ unsigned short f2h(float v){
    _Float16 f = (_Float16)v; unsigned short u; __builtin_memcpy(&u, &f, 2); return u;
}
__device__ __forceinline__ float h2f(unsigned short u){
    _Float16 f; __builtin_memcpy(&f, &u, 2); return (float)f;
}

// ================= merged prep: hist + x-convert + weight prep =================
// block ranges: [0,3125) hist, [3125,9375) convert, [9375,10719) wmsg,
//               [10719,13407) wupd, [13407,13695) mlp
#define HIST_B 3125
#define CONV_B 6250
#define WMSG_B 1344
#define WUPD_B 2688
#define MLP_B  288

__global__ void prep_all(const int* __restrict__ dst, int* counts,
                         const float* __restrict__ x, ushort_t* __restrict__ xf,
                         const float* __restrict__ Wm, ushort_t* wmh, ushort_t* wml,
                         const float* __restrict__ Wu, ushort_t* wuh, ushort_t* wul,
                         const float* __restrict__ W1, const float* __restrict__ W2,
                         const float* __restrict__ W3,
                         ushort_t* w1h, ushort_t* w1l, ushort_t* w2h, ushort_t* w2l,
                         ushort_t* w3h, ushort_t* w3l)
{
    int b = blockIdx.x, t = threadIdx.x;
    if (b < HIST_B){
        int e = b * 256 + t;
        if (e < NE) atomicAdd(&counts[dst[e]], 1);
        return;
    }
    b -= HIST_B;
    if (b < CONV_B){
        int i = b * 256 + t;            // i < NN*32 exactly
        f32x4 v = *reinterpret_cast<const f32x4*>(x + (size_t)i * 4);
        u16x4 h;
#pragma unroll
        for (int j = 0; j < 4; ++j) h[j] = f2h(v[j]);
        *reinterpret_cast<u16x4*>(xf + (size_t)i * 4) = h;
        return;
    }
    b -= CONV_B;
    if (b < WMSG_B){
        int idx = b * 256 + t;
        const int per = 4 * 8 * 512;
        int layer = idx / per, r = idx % per;
        int kk = r / 4096, nt = (r / 512) & 7, lane = (r / 8) & 63, i = r & 7;
        int c = nt * 16 + (lane & 15);
        int k = kk * 32 + (lane >> 4) * 8 + i;
        float w = Wm[(size_t)layer * 16384 + c * 128 + k];
        unsigned short h = f2h(w);
        wmh[idx] = h; wml[idx] = f2h(w - h2f(h));
        return;
    }
    b -= WMSG_B;
    if (b < WUPD_B){
        int idx = b * 256 + t;
        const int per = 8 * 8 * 512;
        int layer = idx / per, r = idx % per;
        int kk = r / 4096, nt = (r / 512) & 7, lane = (r / 8) & 63, i = r & 7;
        int c = nt * 16 + (lane & 15);
        int k = kk * 32 + (lane >> 4) * 8 + i;
        float w = Wu[(size_t)layer * 32768 + c * 256 + k];
        unsigned short h = f2h(w);
        wuh[idx] = h; wul[idx] = f2h(w - h2f(h));
        return;
    }
    b -= WUPD_B;
    {
        int idx = b * 256 + t;          // < 73728
        const float* W; ushort_t *ph, *pl; int NT, Kld, nc, local;
        if (idx < 32768)      { local = idx;         W = W1; ph = w1h; pl = w1l; NT = 16; Kld = 128; nc = 256; }
        else if (idx < 65536) { local = idx - 32768; W = W2; ph = w2h; pl = w2l; NT = 8;  Kld = 256; nc = 128; }
        else                  { local = idx - 65536; W = W3; ph = w3h; pl = w3l; NT = 4;  Kld = 128; nc = 63;  }
        int i = local & 7, lane = (local >> 3) & 63, nt = (local >> 9) % NT, kk = local / (512 * NT);
        int c = nt * 16 + (lane & 15);
        int k = kk * 32 + (lane >> 4) * 8 + i;
        float w = (c < nc) ? W[c * Kld + k] : 0.f;
        unsigned short h = f2h(w);
        ph[local] = h; pl[local] = f2h(w - h2f(h));
    }
}

// ================= CSR scan + scatter =================
__global__ void blocksum_kernel(const int* __restrict__ counts, int* __restrict__ bsum){
    __shared__ int sd[256];
    int i = blockIdx.x * 256 + threadIdx.x;
    int c = (i < NN) ? counts[i] : 0;
    sd[threadIdx.x] = c; __syncthreads();
    for (int o = 128; o > 0; o >>= 1){
        if (threadIdx.x < o) sd[threadIdx.x] += sd[threadIdx.x + o];
        __syncthreads();
    }
    if (threadIdx.x == 0) bsum[blockIdx.x] = sd[0];
}

__global__ void scanb_kernel(const int* __restrict__ bsum, int* __restrict__ boff,
                             int* __restrict__ row_start, int nb){
    __shared__ int sd[256];
    int t = threadIdx.x;
    int v = (t < nb) ? bsum[t] : 0;
    sd[t] = v; __syncthreads();
    for (int o = 1; o < 256; o <<= 1){
        int u = (t >= o) ? sd[t - o] : 0;
        __syncthreads();
        sd[t] += u;
        __syncthreads();
    }
    if (t < nb) boff[t] = sd[t] - v;   // exclusive
    if (t == 0) row_start[NN] = NE;
}

__global__ void localscan_kernel(const int* __restrict__ counts, const int* __restrict__ boff,
                                 int* __restrict__ row_start, int* __restrict__ cursor){
    __shared__ int sd[256];
    int t = threadIdx.x, i = blockIdx.x * 256 + t;
    int c = (i < NN) ? counts[i] : 0;
    sd[t] = c; __syncthreads();
    for (int o = 1; o < 256; o <<= 1){
        int u = (t >= o) ? sd[t - o] : 0;
        __syncthreads();
        sd[t] += u;
        __syncthreads();
    }
    if (i < NN){
        int ex = boff[blockIdx.x] + sd[t] - c;
        row_start[i] = ex; cursor[i] = ex;
    }
}

__global__ void scatter_kernel(const int* __restrict__ src, const int* __restrict__ dst,
                               int* cursor, int* __restrict__ colv){
    int e = blockIdx.x * blockDim.x + threadIdx.x;
    if (e < NE){
        int pos = atomicAdd(&cursor[dst[e]], 1);
        colv[pos] = src[e];
    }
}

// LDS tile rows x 136 ushorts (272-B stride, 16-B aligned, bank-spread)
#define LDS_STRIDE 136

// stage one 16x(NT*16) fp16 tile into LDS at rowBase. ACT: 0 none, 1 relu, 2 tanh
template<int NT, int ACT, bool HAS_BIAS>
__device__ __forceinline__ void epi_stage(
    f32x4 (&acc)[NT], const float* __restrict__ bias, int colOffE,
    ushort_t* lds, int rowBase, int lane)
{
    const int lm = lane & 15;
    const int cr = (lane >> 4) * 4;
#pragma unroll
    for (int nt = 0; nt < NT; ++nt){
        float bv = HAS_BIAS ? bias[colOffE + nt * 16 + lm] : 0.f;
#pragma unroll
        for (int j = 0; j < 4; ++j){
            float v = acc[nt][j] + bv;
            if (ACT == 1) v = v > 0.f ? v : 0.f;
            else if (ACT == 2) v = tanhf(v);
            lds[(rowBase + cr + j) * LDS_STRIDE + nt * 16 + lm] = f2h(v);
        }
    }
}

// flat coalesced flush of a ROWSx128 fp16 tile (call after __syncthreads)
template<int ROWS>
__device__ __forceinline__ void flush_tile(
    const ushort_t* lds, ushort_t* __restrict__ out,
    int blockRow0, int ldcE, int colOffE, int tid)
{
#pragma unroll
    for (int it = 0; it < ROWS / 16; ++it){
        int idx  = it * 256 + tid;        // chunks of 16 B
        int row  = idx >> 4;
        int colE = (idx & 15) * 8;
        int g = blockRow0 + row;
        if (g < NN)
            *reinterpret_cast<s16x8*>(out + (size_t)g * ldcE + colOffE + colE) =
                *reinterpret_cast<const s16x8*>(lds + row * LDS_STRIDE + colE);
    }
}

// cooperative stage of one 32-K chunk of a hi/lo B panel into lds_b
template<int NT>
__device__ __forceinline__ void stage_bN(const ushort_t* __restrict__ Bh,
                                         const ushort_t* __restrict__ Bl,
                                         int kk, int NTtot, int nt0,
                                         ushort_t* lds_b, int w, int lane){
#pragma unroll
    for (int c = w; c < 2 * NT; c += 4){
        const ushort_t* srcW = (c < NT) ? (Bh + ((size_t)(kk * NTtot + nt0 + c)) * 512)
                                        : (Bl + ((size_t)(kk * NTtot + nt0 + (c - NT))) * 512);
        *reinterpret_cast<s16x8*>(&lds_b[c * 512 + lane * 8]) =
            *reinterpret_cast<const s16x8*>(srcW + lane * 8);
    }
}

// generic GEMM with LDS-staged B (all 4 waves share each 32-K chunk)
// OUTMODE: 0 = fp32 direct (Cf), 2 = fp16 LDS-staged (Cs)
template<int KK1, int NT, int ACT, bool HAS_BIAS, int OUTMODE>
__global__ __launch_bounds__(256) void gemm_ldsb(
    const ushort_t* __restrict__ A1,
    const ushort_t* __restrict__ Bh, const ushort_t* __restrict__ Bl, int NTtot,
    const float* __restrict__ bias,
    ushort_t* __restrict__ Cs, float* __restrict__ Cf, int ldcE, int ncols)
{
    __shared__ ushort_t lds_out[OUTMODE == 2 ? 64 * LDS_STRIDE : 16];
    __shared__ ushort_t lds_b[NT * 1024];
    const int tid  = threadIdx.x;
    const int lane = tid & 63;
    const int w    = tid >> 6;
    const int nt0  = blockIdx.y * NT;
    const int colOffE = blockIdx.y * (NT * 16);
    const int waveRow0 = blockIdx.x * 64 + w * 16;
    const int lm = lane & 15;
    const int lk = (lane >> 4) * 8;

    f32x4 acc[NT];
#pragma unroll
    for (int nt = 0; nt < NT; ++nt)
#pragma unroll
        for (int j = 0; j < 4; ++j) acc[nt][j] = 0.f;

#pragma unroll
    for (int kk = 0; kk < KK1; ++kk){
        __syncthreads();                         // previous chunk fully consumed
        stage_bN<NT>(Bh, Bl, kk, NTtot, nt0, lds_b, w, lane);
        __syncthreads();                         // chunk visible to all waves
        f16x8 af = *reinterpret_cast<const f16x8*>(A1 + (size_t)(waveRow0 + lm) * (KK1 * 32) + kk * 32 + lk);
#pragma unroll
        for (int nt = 0; nt < NT; ++nt){
            f16x8 bh = *reinterpret_cast<const f16x8*>(&lds_b[nt * 512 + lane * 8]);
            f16x8 bl = *reinterpret_cast<const f16x8*>(&lds_b[(NT + nt) * 512 + lane * 8]);
            acc[nt] = __builtin_amdgcn_mfma_f32_16x16x32_f16(af, bh, acc[nt], 0, 0, 0);
            acc[nt] = __builtin_amdgcn_mfma_f32_16x16x32_f16(af, bl, acc[nt], 0, 0, 0);
        }
    }

    if constexpr (OUTMODE == 2){
        epi_stage<NT, ACT, HAS_BIAS>(acc, bias, colOffE, lds_out, w * 16, lane);
        __syncthreads();
        flush_tile<64>(lds_out, Cs, blockIdx.x * 64, ldcE, colOffE, tid);
    } else {
        const int cr = (lane >> 4) * 4;
#pragma unroll
        for (int nt = 0; nt < NT; ++nt){
            int col = colOffE + nt * 16 + lm;
            if (col >= ncols) continue;
            float bv = HAS_BIAS ? bias[col] : 0.f;
#pragma unroll
            for (int j = 0; j < 4; ++j){
                int g = waveRow0 + cr + j;
                if (g < NN){
                    float v = acc[nt][j] + bv;
                    if (ACT == 1) v = v > 0.f ? v : 0.f;
                    else if (ACT == 2) v = tanhf(v);
                    Cf[(size_t)g * ldcE + col] = v;
                }
            }
        }
    }
}

// cooperative stage of one 32-K chunk of a hi/lo B panel (16 KB) into lds_b (fused, NT=8)
__device__ __forceinline__ void stage_b16(const ushort_t* __restrict__ Bh,
                                          const ushort_t* __restrict__ Bl,
                                          int kk, ushort_t* lds_b, int w, int lane){
#pragma unroll
    for (int i = 0; i < 4; ++i){
        int c = w * 4 + i;                 // 16 segments x 512 ushorts (1 KB each)
        const ushort_t* srcW = (c < 8) ? (Bh + (size_t)kk * 4096 + c * 512)
                                       : (Bl + (size_t)kk * 4096 + (c - 8) * 512);
        *reinterpret_cast<s16x8*>(&lds_b[c * 512 + lane * 8]) =
            *reinterpret_cast<const s16x8*>(srcW + lane * 8);
    }
}

// fused layer: MT=1 (782 blocks, 3 waves/SIMD) + LDS-staged B (4 waves share each chunk)
// h' = relu([aggr|h] Wu^T) -> h_out ; m' = tanh(h' Wm^T + bm) -> m_out
template<bool WITH_MSG>
__global__ __launch_bounds__(256) void fused_update_msg(
    const ushort_t* __restrict__ ag, const ushort_t* __restrict__ h,
    const ushort_t* __restrict__ Wuh, const ushort_t* __restrict__ Wul,
    const ushort_t* __restrict__ Wmh, const ushort_t* __restrict__ Wml,
    const float* __restrict__ bm,
    ushort_t* __restrict__ h_out, ushort_t* __restrict__ m_out)
{
    __shared__ ushort_t lds_out[64 * LDS_STRIDE];   // 17.4 KB output tile
    __shared__ ushort_t lds_b[8192];                // 16 KB staged B chunk
    const int tid  = threadIdx.x;
    const int lane = tid & 63;
    const int w    = tid >> 6;
    const int waveRow0 = blockIdx.x * 64 + w * 16;
    const int lm = lane & 15;
    const int lk = (lane >> 4) * 8;

    // ---- phase 1: h' = relu([ag|h] Wu^T), K=256 in 8 chunks of 32 ----
    f32x4 acc[8];
#pragma unroll
    for (int nt = 0; nt < 8; ++nt)
#pragma unroll
        for (int j = 0; j < 4; ++j) acc[nt][j] = 0.f;

#pragma unroll
    for (int kk = 0; kk < 8; ++kk){
        __syncthreads();                            // prev chunk fully consumed
        stage_b16(Wuh, Wul, kk, lds_b, w, lane);
        __syncthreads();                            // chunk visible to all waves
        const ushort_t* ap = (kk < 4) ? ag : h;
        const int kc = (kk & 3) * 32 + lk;
        f16x8 af = *reinterpret_cast<const f16x8*>(ap + (size_t)(waveRow0 + lm) * 128 + kc);
#pragma unroll
        for (int nt = 0; nt < 8; ++nt){
            f16x8 bh = *reinterpret_cast<const f16x8*>(&lds_b[nt * 512 + lane * 8]);
            f16x8 bl = *reinterpret_cast<const f16x8*>(&lds_b[4096 + nt * 512 + lane * 8]);
            acc[nt] = __builtin_amdgcn_mfma_f32_16x16x32_f16(af, bh, acc[nt], 0, 0, 0);
            acc[nt] = __builtin_amdgcn_mfma_f32_16x16x32_f16(af, bl, acc[nt], 0, 0, 0);
        }
    }
    epi_stage<8, 1, false>(acc, nullptr, 0, lds_out, w * 16, lane);
    __syncthreads();
    flush_tile<64>(lds_out, h_out, blockIdx.x * 64, 128, 0, tid);

    if constexpr (WITH_MSG){
        // ---- phase 2: m' = tanh(h' Wm^T + bm), A = h' from lds_out (own rows) ----
        f32x4 acc2[8];
#pragma unroll
        for (int nt = 0; nt < 8; ++nt)
#pragma unroll
            for (int j = 0; j < 4; ++j) acc2[nt][j] = 0.f;
#pragma unroll
        for (int kk = 0; kk < 4; ++kk){
            __syncthreads();                        // also fences flush reads before 1st overwrite
            stage_b16(Wmh, Wml, kk, lds_b, w, lane);
            __syncthreads();
            f16x8 af = *reinterpret_cast<const f16x8*>(&lds_out[(w * 16 + lm) * LDS_STRIDE + kk * 32 + lk]);
#pragma unroll
            for (int nt = 0; nt < 8; ++nt){
                f16x8 bh = *reinterpret_cast<const f16x8*>(&lds_b[nt * 512 + lane * 8]);
                f16x8 bl = *reinterpret_cast<const f16x8*>(&lds_b[4096 + nt * 512 + lane * 8]);
                acc2[nt] = __builtin_amdgcn_mfma_f32_16x16x32_f16(af, bh, acc2[nt], 0, 0, 0);
                acc2[nt] = __builtin_amdgcn_mfma_f32_16x16x32_f16(af, bl, acc2[nt], 0, 0, 0);
            }
        }
        // each wave writes only its own lds_out rows after its own last read of them
        epi_stage<8, 2, true>(acc2, bm, 0, lds_out, w * 16, lane);
        __syncthreads();
        flush_tile<64>(lds_out, m_out, blockIdx.x * 64, 128, 0, tid);
    }
}

// ================= aggregation: one wave per node, 4 edge-rows per dwordx4, 8 in flight =================
__global__ __launch_bounds__(256) void aggregate_kernel(
    const ushort_t* __restrict__ m,
    const int* __restrict__ row_start, const int* __restrict__ cols,
    ushort_t* __restrict__ ag)
{
    int wid  = (blockIdx.x * 256 + threadIdx.x) >> 6;   // node (grid exact: NN/4 blocks)
    int lane = threadIdx.x & 63;
    int g    = lane >> 4;
    int fl   = lane & 15;
    int s0 = row_start[wid], s1 = row_start[wid + 1];

    float a[8];
#pragma unroll
    for (int j = 0; j < 8; ++j) a[j] = 0.f;

    if (g == 0){
        f16x8 v = *reinterpret_cast<const f16x8*>(m + (size_t)wid * 128 + fl * 8);
#pragma unroll
        for (int j = 0; j < 8; ++j) a[j] += (float)v[j];
    }

    int e = s0;
    for (; e + 31 < s1; e += 32){               // 8 independent 1-KB gathers in flight
        f16x8 v0 = *reinterpret_cast<const f16x8*>(m + (size_t)cols[e      + g] * 128 + fl * 8);
        f16x8 v1 = *reinterpret_cast<const f16x8*>(m + (size_t)cols[e + 4  + g] * 128 + fl * 8);
        f16x8 v2 = *reinterpret_cast<const f16x8*>(m + (size_t)cols[e + 8  + g] * 128 + fl * 8);
        f16x8 v3 = *reinterpret_cast<const f16x8*>(m + (size_t)cols[e + 12 + g] * 128 + fl * 8);
        f16x8 v4 = *reinterpret_cast<const f16x8*>(m + (size_t)cols[e + 16 + g] * 128 + fl * 8);
        f16x8 v5 = *reinterpret_cast<const f16x8*>(m + (size_t)cols[e + 20 + g] * 128 + fl * 8);
        f16x8 v6 = *reinterpret_cast<const f16x8*>(m + (size_t)cols[e + 24 + g] * 128 + fl * 8);
        f16x8 v7 = *reinterpret_cast<const f16x8*>(m + (size_t)cols[e + 28 + g] * 128 + fl * 8);
#pragma unroll
        for (int j = 0; j < 8; ++j)
            a[j] += (((float)v0[j] + (float)v1[j]) + ((float)v2[j] + (float)v3[j]))
                  + (((float)v4[j] + (float)v5[j]) + ((float)v6[j] + (float)v7[j]));
    }
    for (; e + 15 < s1; e += 16){               // 4 in flight
        f16x8 v0 = *reinterpret_cast<const f16x8*>(m + (size_t)cols[e      + g] * 128 + fl * 8);
        f16x8 v1 = *reinterpret_cast<const f16x8*>(m + (size_t)cols[e + 4  + g] * 128 + fl * 8);
        f16x8 v2 = *reinterpret_cast<const f16x8*>(m + (size_t)cols[e + 8  + g] * 128 + fl * 8);
        f16x8 v3 = *reinterpret_cast<const f16x8*>(m + (size_t)cols[e + 12 + g] * 128 + fl * 8);
#pragma unroll
        for (int j = 0; j < 8; ++j)
            a[j] += ((float)v0[j] + (float)v1[j]) + ((float)v2[j] + (float)v3[j]);
    }
    for (; e + 7 < s1; e += 8){
        f16x8 v0 = *reinterpret_cast<const f16x8*>(m + (size_t)cols[e     + g] * 128 + fl * 8);
        f16x8 v1 = *reinterpret_cast<const f16x8*>(m + (size_t)cols[e + 4 + g] * 128 + fl * 8);
#pragma unroll
        for (int j = 0; j < 8; ++j) a[j] += (float)v0[j] + (float)v1[j];
    }
    for (; e < s1; e += 4){
        int idx = e + g;
        if (idx < s1){
            f16x8 v0 = *reinterpret_cast<const f16x8*>(m + (size_t)cols[idx] * 128 + fl * 8);
#pragma unroll
            for (int j = 0; j < 8; ++j) a[j] += (float)v0[j];
        }
    }

#pragma unroll
    for (int j = 0; j < 8; ++j){
        a[j] += __shfl_xor(a[j], 16);
        a[j] += __shfl_xor(a[j], 32);
    }

    if (g == 0){
        s16x8 outv;
#pragma unroll
        for (int j = 0; j < 8; ++j) outv[j] = (short)f2h(a[j]);
        *reinterpret_cast<s16x8*>(ag + (size_t)wid * 128 + fl * 8) = outv;
    }
}

// ================= host =================
extern "C" void kernel_launch(void* const* d_in, const int* in_sizes, int n_in,
                              void* d_out, int out_size, void* d_ws, size_t ws_size,
                              hipStream_t stream)
{
    const float* x     = (const float*)d_in[0];
    const int*   ei    = (const int*)d_in[1];
    const float* W_msg = (const float*)d_in[3];
    const float* b_msg = (const float*)d_in[4];
    const float* W_upd = (const float*)d_in[5];
    const float* W1    = (const float*)d_in[6];
    const float* b1    = (const float*)d_in[7];
    const float* W2    = (const float*)d_in[8];
    const float* b2    = (const float*)d_in[9];
    const float* W3    = (const float*)d_in[10];
    const float* b3    = (const float*)d_in[11];
    const int* srcp = ei;
    const int* dstp = ei + NE;

    char* ws = (char*)d_ws;
    size_t off = 0;
    auto carve = [&](size_t bytes) -> void* {
        void* p = ws + off;
        off += (bytes + 255) & ~(size_t)255;
        return p;
    };
    const size_t FBUF = (size_t)NN * 128 * 2;   // 12.8 MB fp16 node buffer
    // carve order: (m, ag) adjacent -> h1 (N x 256 fp16) overlay
    ushort_t* xf = (ushort_t*)carve(FBUF);      // x fp16 / h ping / h2 in head
    ushort_t* hA = (ushort_t*)carve(FBUF);      // h pong
    ushort_t* m  = (ushort_t*)carve(FBUF);      // messages; h1 lo half in head
    ushort_t* ag = (ushort_t*)carve(FBUF);      // aggr;     h1 hi half in head

    int* counts    = (int*)carve((size_t)NN * 4);
    int* cursor    = (int*)carve((size_t)NN * 4);
    int* row_start = (int*)carve(((size_t)NN + 1) * 4);
    int* bsum      = (int*)carve(256 * 4);
    int* boff      = (int*)carve(256 * 4);
    int* colv      = (int*)carve((size_t)NE * 4);

    ushort_t* wmsg_hi = (ushort_t*)carve((size_t)21 * 16384 * 2);
    ushort_t* wmsg_lo = (ushort_t*)carve((size_t)21 * 16384 * 2);
    ushort_t* wupd_hi = (ushort_t*)carve((size_t)21 * 32768 * 2);
    ushort_t* wupd_lo = (ushort_t*)carve((size_t)21 * 32768 * 2);
    ushort_t* w1_hi   = (ushort_t*)carve(32768 * 2);
    ushort_t* w1_lo   = (ushort_t*)carve(32768 * 2);
    ushort_t* w2_hi   = (ushort_t*)carve(32768 * 2);
    ushort_t* w2_lo   = (ushort_t*)carve(32768 * 2);
    ushort_t* w3_hi   = (ushort_t*)carve(8192 * 2);
    ushort_t* w3_lo   = (ushort_t*)carve(8192 * 2);
    (void)carve(65536);   // tail pad: unguarded A-loads overrun < 13 KB

    const int NB = (NN + 255) / 256;   // 196
    const int GB = (NN + 63) / 64;     // 782

    // merged prep (hist + convert + all weight prep) then CSR scan + scatter
    hipMemsetAsync(counts, 0, (size_t)NN * 4, stream);
    prep_all<<<HIST_B + CONV_B + WMSG_B + WUPD_B + MLP_B, 256, 0, stream>>>(
        dstp, counts, x, xf,
        W_msg, wmsg_hi, wmsg_lo,
        W_upd, wupd_hi, wupd_lo,
        W1, W2, W3, w1_hi, w1_lo, w2_hi, w2_lo, w3_hi, w3_lo);
    blocksum_kernel<<<NB, 256, 0, stream>>>(counts, bsum);
    scanb_kernel<<<1, 256, 0, stream>>>(bsum, boff, row_start, NB);
    localscan_kernel<<<NB, 256, 0, stream>>>(counts, boff, row_start, cursor);
    scatter_kernel<<<(NE + 255) / 256, 256, 0, stream>>>(srcp, dstp, cursor, colv);

    // m_0 = tanh(x Wm_0^T + bm_0)
    gemm_ldsb<4, 8, 2, true, 2><<<GB, 256, 0, stream>>>(
        xf, wmsg_hi, wmsg_lo, 8, b_msg, m, nullptr, 128, 128);

    // 21 layers; h ping-pongs xf <-> hA
    const ushort_t* cur = xf;
    ushort_t* nxt = hA;
    for (int l = 0; l < 21; ++l){
        aggregate_kernel<<<NN / 4, 256, 0, stream>>>(m, row_start, colv, ag);
        if (l < 20){
            fused_update_msg<true><<<GB, 256, 0, stream>>>(
                ag, cur,
                wupd_hi + (size_t)l * 32768, wupd_lo + (size_t)l * 32768,
                wmsg_hi + (size_t)(l + 1) * 16384, wmsg_lo + (size_t)(l + 1) * 16384,
                b_msg + (size_t)(l + 1) * 128,
                nxt, m);
        } else {
            fused_update_msg<false><<<GB, 256, 0, stream>>>(
                ag, cur,
                wupd_hi + (size_t)l * 32768, wupd_lo + (size_t)l * 32768,
                nullptr, nullptr, nullptr,
                nxt, nullptr);
        }
        const ushort_t* t = cur; cur = nxt; nxt = (ushort_t*)t;
    }
    // after 21 layers: cur == hA; xf, m, ag free

    // MLP head: h1 (N x 256 fp16) overlays m..ag span; h2 = xf
    ushort_t* h1 = m;
    gemm_ldsb<4, 8, 1, true, 2><<<dim3(GB, 2), 256, 0, stream>>>(
        cur, w1_hi, w1_lo, 16, b1, h1, nullptr, 256, 256);
    gemm_ldsb<8, 8, 1, true, 2><<<GB, 256, 0, stream>>>(
        h1, w2_hi, w2_lo, 8, b2, xf, nullptr, 128, 128);
    gemm_ldsb<4, 4, 0, true, 0><<<GB, 256, 0, stream>>>(
        xf, w3_hi, w3_lo, 4, b3, nullptr, (float*)d_out, 63, 63);
}

// Round 13
// 1403.417 us; speedup vs baseline: 1.0976x; 1.0976x over previous
//
#include <hip/hip_runtime.h>
#include <cstdint>

#define NN 50000
#define NE 800000

typedef __attribute__((ext_vector_type(8))) short    s16x8;
typedef __attribute__((ext_vector_type(4))) float    f32x4;
typedef __attribute__((ext_vector_type(4))) unsigned short u16x4;
typedef _Float16 f16x8 __attribute__((ext_vector_type(8)));

typedef unsigned short ushort_t;
typedef unsigned int   uint_t;

__device__ __forceinline__ unsigned short f2h(float v){
    _Float16 f = (_Float16)v; unsigned short u; __builtin_memcpy(&u, &f, 2); return u;
}
__device__ __forceinline__ float h2f(unsigned short u){
    _Float16 f; __builtin_memcpy(&f, &u, 2); return (float)f;
}

// ================= merged prep: hist + x-convert + weight prep =================
#define HIST_B 3125
#define CONV_B 6250
#define WMSG_B 1344
#define WUPD_B 2688
#define MLP_B  288

__global__ void prep_all(const int* __restrict__ dst, int* counts,
                         const float* __restrict__ x, ushort_t* __restrict__ xf,
                         const float* __restrict__ Wm, ushort_t* wmh, ushort_t* wml,
                         const float* __restrict__ Wu, ushort_t* wuh, ushort_t* wul,
                         const float* __restrict__ W1, const float* __restrict__ W2,
                         const float* __restrict__ W3,
                         ushort_t* w1h, ushort_t* w1l, ushort_t* w2h, ushort_t* w2l,
                         ushort_t* w3h, ushort_t* w3l)
{
    int b = blockIdx.x, t = threadIdx.x;
    if (b < HIST_B){
        int e = b * 256 + t;
        if (e < NE) atomicAdd(&counts[dst[e]], 1);
        return;
    }
    b -= HIST_B;
    if (b < CONV_B){
        int i = b * 256 + t;            // i < NN*32 exactly
        f32x4 v = *reinterpret_cast<const f32x4*>(x + (size_t)i * 4);
        u16x4 h;
#pragma unroll
        for (int j = 0; j < 4; ++j) h[j] = f2h(v[j]);
        *reinterpret_cast<u16x4*>(xf + (size_t)i * 4) = h;
        return;
    }
    b -= CONV_B;
    if (b < WMSG_B){
        int idx = b * 256 + t;
        const int per = 4 * 8 * 512;
        int layer = idx / per, r = idx % per;
        int kk = r / 4096, nt = (r / 512) & 7, lane = (r / 8) & 63, i = r & 7;
        int c = nt * 16 + (lane & 15);
        int k = kk * 32 + (lane >> 4) * 8 + i;
        float w = Wm[(size_t)layer * 16384 + c * 128 + k];
        unsigned short h = f2h(w);
        wmh[idx] = h; wml[idx] = f2h(w - h2f(h));
        return;
    }
    b -= WMSG_B;
    if (b < WUPD_B){
        int idx = b * 256 + t;
        const int per = 8 * 8 * 512;
        int layer = idx / per, r = idx % per;
        int kk = r / 4096, nt = (r / 512) & 7, lane = (r / 8) & 63, i = r & 7;
        int c = nt * 16 + (lane & 15);
        int k = kk * 32 + (lane >> 4) * 8 + i;
        float w = Wu[(size_t)layer * 32768 + c * 256 + k];
        unsigned short h = f2h(w);
        wuh[idx] = h; wul[idx] = f2h(w - h2f(h));
        return;
    }
    b -= WUPD_B;
    {
        int idx = b * 256 + t;          // < 73728
        const float* W; ushort_t *ph, *pl; int NT, Kld, nc, local;
        if (idx < 32768)      { local = idx;         W = W1; ph = w1h; pl = w1l; NT = 16; Kld = 128; nc = 256; }
        else if (idx < 65536) { local = idx - 32768; W = W2; ph = w2h; pl = w2l; NT = 8;  Kld = 256; nc = 128; }
        else                  { local = idx - 65536; W = W3; ph = w3h; pl = w3l; NT = 4;  Kld = 128; nc = 63;  }
        int i = local & 7, lane = (local >> 3) & 63, nt = (local >> 9) % NT, kk = local / (512 * NT);
        int c = nt * 16 + (lane & 15);
        int k = kk * 32 + (lane >> 4) * 8 + i;
        float w = (c < nc) ? W[c * Kld + k] : 0.f;
        unsigned short h = f2h(w);
        ph[local] = h; pl[local] = f2h(w - h2f(h));
    }
}

// ================= CSR scan + scatter =================
__global__ void blocksum_kernel(const int* __restrict__ counts, int* __restrict__ bsum){
    __shared__ int sd[256];
    int i = blockIdx.x * 256 + threadIdx.x;
    int c = (i < NN) ? counts[i] : 0;
    sd[threadIdx.x] = c; __syncthreads();
    for (int o = 128; o > 0; o >>= 1){
        if (threadIdx.x < o) sd[threadIdx.x] += sd[threadIdx.x + o];
        __syncthreads();
    }
    if (threadIdx.x == 0) bsum[blockIdx.x] = sd[0];
}

__global__ void scanb_kernel(const int* __restrict__ bsum, int* __restrict__ boff,
                             int* __restrict__ row_start, int nb){
    __shared__ int sd[256];
    int t = threadIdx.x;
    int v = (t < nb) ? bsum[t] : 0;
    sd[t] = v; __syncthreads();
    for (int o = 1; o < 256; o <<= 1){
        int u = (t >= o) ? sd[t - o] : 0;
        __syncthreads();
        sd[t] += u;
        __syncthreads();
    }
    if (t < nb) boff[t] = sd[t] - v;   // exclusive
    if (t == 0) row_start[NN] = NE;
}

__global__ void localscan_kernel(const int* __restrict__ counts, const int* __restrict__ boff,
                                 int* __restrict__ row_start, int* __restrict__ cursor){
    __shared__ int sd[256];
    int t = threadIdx.x, i = blockIdx.x * 256 + t;
    int c = (i < NN) ? counts[i] : 0;
    sd[t] = c; __syncthreads();
    for (int o = 1; o < 256; o <<= 1){
        int u = (t >= o) ? sd[t - o] : 0;
        __syncthreads();
        sd[t] += u;
        __syncthreads();
    }
    if (i < NN){
        int ex = boff[blockIdx.x] + sd[t] - c;
        row_start[i] = ex; cursor[i] = ex;
    }
}

__global__ void scatter_kernel(const int* __restrict__ src, const int* __restrict__ dst,
                               int* cursor, int* __restrict__ colv){
    int e = blockIdx.x * blockDim.x + threadIdx.x;
    if (e < NE){
        int pos = atomicAdd(&cursor[dst[e]], 1);
        colv[pos] = src[e];
    }
}

// LDS tile rows x 136 ushorts (272-B stride, 16-B aligned, bank-spread)
#define LDS_STRIDE 136

// stage one 16x(NT*16) fp16 tile into LDS at rowBase. ACT: 0 none, 1 relu, 2 tanh
template<int NT, int ACT, bool HAS_BIAS>
__device__ __forceinline__ void epi_stage(
    f32x4 (&acc)[NT], const float* __restrict__ bias, int colOffE,
    ushort_t* lds, int rowBase, int lane)
{
    const int lm = lane & 15;
    const int cr = (lane >> 4) * 4;
#pragma unroll
    for (int nt = 0; nt < NT; ++nt){
        float bv = HAS_BIAS ? bias[colOffE + nt * 16 + lm] : 0.f;
#pragma unroll
        for (int j = 0; j < 4; ++j){
            float v = acc[nt][j] + bv;
            if (ACT == 1) v = v > 0.f ? v : 0.f;
            else if (ACT == 2) v = tanhf(v);
            lds[(rowBase + cr + j) * LDS_STRIDE + nt * 16 + lm] = f2h(v);
        }
    }
}

// flat coalesced flush of a ROWSx128 fp16 tile (call after __syncthreads)
template<int ROWS>
__device__ __forceinline__ void flush_tile(
    const ushort_t* lds, ushort_t* __restrict__ out,
    int blockRow0, int ldcE, int colOffE, int tid)
{
#pragma unroll
    for (int it = 0; it < ROWS / 16; ++it){
        int idx  = it * 256 + tid;        // chunks of 16 B
        int row  = idx >> 4;
        int colE = (idx & 15) * 8;
        int g = blockRow0 + row;
        if (g < NN)
            *reinterpret_cast<s16x8*>(out + (size_t)g * ldcE + colOffE + colE) =
                *reinterpret_cast<const s16x8*>(lds + row * LDS_STRIDE + colE);
    }
}

// cooperative stage of one 32-K chunk of a hi/lo B panel into lds_b
template<int NT>
__device__ __forceinline__ void stage_bN(const ushort_t* __restrict__ Bh,
                                         const ushort_t* __restrict__ Bl,
                                         int kk, int NTtot, int nt0,
                                         ushort_t* lds_b, int w, int lane){
#pragma unroll
    for (int c = w; c < 2 * NT; c += 4){
        const ushort_t* srcW = (c < NT) ? (Bh + ((size_t)(kk * NTtot + nt0 + c)) * 512)
                                        : (Bl + ((size_t)(kk * NTtot + nt0 + (c - NT))) * 512);
        *reinterpret_cast<s16x8*>(&lds_b[c * 512 + lane * 8]) =
            *reinterpret_cast<const s16x8*>(srcW + lane * 8);
    }
}

// generic GEMM with LDS-staged B (all 4 waves share each 32-K chunk)
// OUTMODE: 0 = fp32 direct (Cf), 2 = fp16 LDS-staged (Cs)
template<int KK1, int NT, int ACT, bool HAS_BIAS, int OUTMODE>
__global__ __launch_bounds__(256) void gemm_ldsb(
    const ushort_t* __restrict__ A1,
    const ushort_t* __restrict__ Bh, const ushort_t* __restrict__ Bl, int NTtot,
    const float* __restrict__ bias,
    ushort_t* __restrict__ Cs, float* __restrict__ Cf, int ldcE, int ncols)
{
    __shared__ ushort_t lds_out[OUTMODE == 2 ? 64 * LDS_STRIDE : 16];
    __shared__ ushort_t lds_b[NT * 1024];
    const int tid  = threadIdx.x;
    const int lane = tid & 63;
    const int w    = tid >> 6;
    const int nt0  = blockIdx.y * NT;
    const int colOffE = blockIdx.y * (NT * 16);
    const int waveRow0 = blockIdx.x * 64 + w * 16;
    const int lm = lane & 15;
    const int lk = (lane >> 4) * 8;

    f32x4 acc[NT];
#pragma unroll
    for (int nt = 0; nt < NT; ++nt)
#pragma unroll
        for (int j = 0; j < 4; ++j) acc[nt][j] = 0.f;

#pragma unroll
    for (int kk = 0; kk < KK1; ++kk){
        __syncthreads();                         // previous chunk fully consumed
        stage_bN<NT>(Bh, Bl, kk, NTtot, nt0, lds_b, w, lane);
        __syncthreads();                         // chunk visible to all waves
        f16x8 af = *reinterpret_cast<const f16x8*>(A1 + (size_t)(waveRow0 + lm) * (KK1 * 32) + kk * 32 + lk);
#pragma unroll
        for (int nt = 0; nt < NT; ++nt){
            f16x8 bh = *reinterpret_cast<const f16x8*>(&lds_b[nt * 512 + lane * 8]);
            f16x8 bl = *reinterpret_cast<const f16x8*>(&lds_b[(NT + nt) * 512 + lane * 8]);
            acc[nt] = __builtin_amdgcn_mfma_f32_16x16x32_f16(af, bh, acc[nt], 0, 0, 0);
            acc[nt] = __builtin_amdgcn_mfma_f32_16x16x32_f16(af, bl, acc[nt], 0, 0, 0);
        }
    }

    if constexpr (OUTMODE == 2){
        epi_stage<NT, ACT, HAS_BIAS>(acc, bias, colOffE, lds_out, w * 16, lane);
        __syncthreads();
        flush_tile<64>(lds_out, Cs, blockIdx.x * 64, ldcE, colOffE, tid);
    } else {
        const int cr = (lane >> 4) * 4;
#pragma unroll
        for (int nt = 0; nt < NT; ++nt){
            int col = colOffE + nt * 16 + lm;
            if (col >= ncols) continue;
            float bv = HAS_BIAS ? bias[col] : 0.f;
#pragma unroll
            for (int j = 0; j < 4; ++j){
                int g = waveRow0 + cr + j;
                if (g < NN){
                    float v = acc[nt][j] + bv;
                    if (ACT == 1) v = v > 0.f ? v : 0.f;
                    else if (ACT == 2) v = tanhf(v);
                    Cf[(size_t)g * ldcE + col] = v;
                }
            }
        }
    }
}

// cooperative stage of one 32-K chunk of a hi/lo B panel (16 KB) into lds_b (fused, NT=8)
__device__ __forceinline__ void stage_b16(const ushort_t* __restrict__ Bh,
                                          const ushort_t* __restrict__ Bl,
                                          int kk, ushort_t* lds_b, int w, int lane){
#pragma unroll
    for (int i = 0; i < 4; ++i){
        int c = w * 4 + i;                 // 16 segments x 512 ushorts (1 KB each)
        const ushort_t* srcW = (c < 8) ? (Bh + (size_t)kk * 4096 + c * 512)
                                       : (Bl + (size_t)kk * 4096 + (c - 8) * 512);
        *reinterpret_cast<s16x8*>(&lds_b[c * 512 + lane * 8]) =
            *reinterpret_cast<const s16x8*>(srcW + lane * 8);
    }
}

// fused layer: MT=1 (782 blocks, 3 waves/SIMD) + LDS-staged B (4 waves share each chunk)
// h' = relu([aggr|h] Wu^T) -> h_out ; m' = tanh(h' Wm^T + bm) -> m_out
template<bool WITH_MSG>
__global__ __launch_bounds__(256) void fused_update_msg(
    const ushort_t* __restrict__ ag, const ushort_t* __restrict__ h,
    const ushort_t* __restrict__ Wuh, const ushort_t* __restrict__ Wul,
    const ushort_t* __restrict__ Wmh, const ushort_t* __restrict__ Wml,
    const float* __restrict__ bm,
    ushort_t* __restrict__ h_out, ushort_t* __restrict__ m_out)
{
    __shared__ ushort_t lds_out[64 * LDS_STRIDE];   // 17.4 KB output tile
    __shared__ ushort_t lds_b[8192];                // 16 KB staged B chunk
    const int tid  = threadIdx.x;
    const int lane = tid & 63;
    const int w    = tid >> 6;
    const int waveRow0 = blockIdx.x * 64 + w * 16;
    const int lm = lane & 15;
    const int lk = (lane >> 4) * 8;

    // ---- phase 1: h' = relu([ag|h] Wu^T), K=256 in 8 chunks of 32 ----
    f32x4 acc[8];
#pragma unroll
    for (int nt = 0; nt < 8; ++nt)
#pragma unroll
        for (int j = 0; j < 4; ++j) acc[nt][j] = 0.f;

#pragma unroll
    for (int kk = 0; kk < 8; ++kk){
        __syncthreads();                            // prev chunk fully consumed
        stage_b16(Wuh, Wul, kk, lds_b, w, lane);
        __syncthreads();                            // chunk visible to all waves
        const ushort_t* ap = (kk < 4) ? ag : h;
        const int kc = (kk & 3) * 32 + lk;
        f16x8 af = *reinterpret_cast<const f16x8*>(ap + (size_t)(waveRow0 + lm) * 128 + kc);
#pragma unroll
        for (int nt = 0; nt < 8; ++nt){
            f16x8 bh = *reinterpret_cast<const f16x8*>(&lds_b[nt * 512 + lane * 8]);
            f16x8 bl = *reinterpret_cast<const f16x8*>(&lds_b[4096 + nt * 512 + lane * 8]);
            acc[nt] = __builtin_amdgcn_mfma_f32_16x16x32_f16(af, bh, acc[nt], 0, 0, 0);
            acc[nt] = __builtin_amdgcn_mfma_f32_16x16x32_f16(af, bl, acc[nt], 0, 0, 0);
        }
    }
    epi_stage<8, 1, false>(acc, nullptr, 0, lds_out, w * 16, lane);
    __syncthreads();
    flush_tile<64>(lds_out, h_out, blockIdx.x * 64, 128, 0, tid);

    if constexpr (WITH_MSG){
        // ---- phase 2: m' = tanh(h' Wm^T + bm), A = h' from lds_out (own rows) ----
        f32x4 acc2[8];
#pragma unroll
        for (int nt = 0; nt < 8; ++nt)
#pragma unroll
            for (int j = 0; j < 4; ++j) acc2[nt][j] = 0.f;
#pragma unroll
        for (int kk = 0; kk < 4; ++kk){
            __syncthreads();                        // also fences flush reads before 1st overwrite
            stage_b16(Wmh, Wml, kk, lds_b, w, lane);
            __syncthreads();
            f16x8 af = *reinterpret_cast<const f16x8*>(&lds_out[(w * 16 + lm) * LDS_STRIDE + kk * 32 + lk]);
#pragma unroll
            for (int nt = 0; nt < 8; ++nt){
                f16x8 bh = *reinterpret_cast<const f16x8*>(&lds_b[nt * 512 + lane * 8]);
                f16x8 bl = *reinterpret_cast<const f16x8*>(&lds_b[4096 + nt * 512 + lane * 8]);
                acc2[nt] = __builtin_amdgcn_mfma_f32_16x16x32_f16(af, bh, acc2[nt], 0, 0, 0);
                acc2[nt] = __builtin_amdgcn_mfma_f32_16x16x32_f16(af, bl, acc2[nt], 0, 0, 0);
            }
        }
        // each wave writes only its own lds_out rows after its own last read of them
        epi_stage<8, 2, true>(acc2, bm, 0, lds_out, w * 16, lane);
        __syncthreads();
        flush_tile<64>(lds_out, m_out, blockIdx.x * 64, 128, 0, tid);
    }
}

// ================= aggregation: one wave per node, 4 edge-rows per dwordx4 (round-11 exact) =================
__global__ __launch_bounds__(256) void aggregate_kernel(
    const ushort_t* __restrict__ m,
    const int* __restrict__ row_start, const int* __restrict__ cols,
    ushort_t* __restrict__ ag)
{
    int wid  = (blockIdx.x * 256 + threadIdx.x) >> 6;   // node (grid exact: NN/4 blocks)
    int lane = threadIdx.x & 63;
    int g    = lane >> 4;
    int fl   = lane & 15;
    int s0 = row_start[wid], s1 = row_start[wid + 1];

    float a[8];
#pragma unroll
    for (int j = 0; j < 8; ++j) a[j] = 0.f;

    if (g == 0){
        f16x8 v = *reinterpret_cast<const f16x8*>(m + (size_t)wid * 128 + fl * 8);
#pragma unroll
        for (int j = 0; j < 8; ++j) a[j] += (float)v[j];
    }

    int e = s0;
    for (; e + 15 < s1; e += 16){               // 4 independent 1-KB gathers in flight
        f16x8 v0 = *reinterpret_cast<const f16x8*>(m + (size_t)cols[e      + g] * 128 + fl * 8);
        f16x8 v1 = *reinterpret_cast<const f16x8*>(m + (size_t)cols[e + 4  + g] * 128 + fl * 8);
        f16x8 v2 = *reinterpret_cast<const f16x8*>(m + (size_t)cols[e + 8  + g] * 128 + fl * 8);
        f16x8 v3 = *reinterpret_cast<const f16x8*>(m + (size_t)cols[e + 12 + g] * 128 + fl * 8);
#pragma unroll
        for (int j = 0; j < 8; ++j)
            a[j] += ((float)v0[j] + (float)v1[j]) + ((float)v2[j] + (float)v3[j]);
    }
    for (; e + 7 < s1; e += 8){
        f16x8 v0 = *reinterpret_cast<const f16x8*>(m + (size_t)cols[e     + g] * 128 + fl * 8);
        f16x8 v1 = *reinterpret_cast<const f16x8*>(m + (size_t)cols[e + 4 + g] * 128 + fl * 8);
#pragma unroll
        for (int j = 0; j < 8; ++j) a[j] += (float)v0[j] + (float)v1[j];
    }
    for (; e < s1; e += 4){
        int idx = e + g;
        if (idx < s1){
            f16x8 v0 = *reinterpret_cast<const f16x8*>(m + (size_t)cols[idx] * 128 + fl * 8);
#pragma unroll
            for (int j = 0; j < 8; ++j) a[j] += (float)v0[j];
        }
    }

#pragma unroll
    for (int j = 0; j < 8; ++j){
        a[j] += __shfl_xor(a[j], 16);
        a[j] += __shfl_xor(a[j], 32);
    }

    if (g == 0){
        s16x8 outv;
#pragma unroll
        for (int j = 0; j < 8; ++j) outv[j] = (short)f2h(a[j]);
        *reinterpret_cast<s16x8*>(ag + (size_t)wid * 128 + fl * 8) = outv;
    }
}

// ================= host =================
extern "C" void kernel_launch(void* const* d_in, const int* in_sizes, int n_in,
                              void* d_out, int out_size, void* d_ws, size_t ws_size,
                              hipStream_t stream)
{
    const float* x     = (const float*)d_in[0];
    const int*   ei    = (const int*)d_in[1];
    const float* W_msg = (const float*)d_in[3];
    const float* b_msg = (const float*)d_in[4];
    const float* W_upd = (const float*)d_in[5];
    const float* W1    = (const float*)d_in[6];
    const float* b1    = (const float*)d_in[7];
    const float* W2    = (const float*)d_in[8];
    const float* b2    = (const float*)d_in[9];
    const float* W3    = (const float*)d_in[10];
    const float* b3    = (const float*)d_in[11];
    const int* srcp = ei;
    const int* dstp = ei + NE;

    char* ws = (char*)d_ws;
    size_t off = 0;
    auto carve = [&](size_t bytes) -> void* {
        void* p = ws + off;
        off += (bytes + 255) & ~(size_t)255;
        return p;
    };
    const size_t FBUF = (size_t)NN * 128 * 2;   // 12.8 MB fp16 node buffer
    // carve order: (m, ag) adjacent -> h1 (N x 256 fp16) overlay
    ushort_t* xf = (ushort_t*)carve(FBUF);      // x fp16 / h ping / h2 in head
    ushort_t* hA = (ushort_t*)carve(FBUF);      // h pong
    ushort_t* m  = (ushort_t*)carve(FBUF);      // messages; h1 lo half in head
    ushort_t* ag = (ushort_t*)carve(FBUF);      // aggr;     h1 hi half in head

    int* counts    = (int*)carve((size_t)NN * 4);
    int* cursor    = (int*)carve((size_t)NN * 4);
    int* row_start = (int*)carve(((size_t)NN + 1) * 4);
    int* bsum      = (int*)carve(256 * 4);
    int* boff      = (int*)carve(256 * 4);
    int* colv      = (int*)carve((size_t)NE * 4);

    ushort_t* wmsg_hi = (ushort_t*)carve((size_t)21 * 16384 * 2);
    ushort_t* wmsg_lo = (ushort_t*)carve((size_t)21 * 16384 * 2);
    ushort_t* wupd_hi = (ushort_t*)carve((size_t)21 * 32768 * 2);
    ushort_t* wupd_lo = (ushort_t*)carve((size_t)21 * 32768 * 2);
    ushort_t* w1_hi   = (ushort_t*)carve(32768 * 2);
    ushort_t* w1_lo   = (ushort_t*)carve(32768 * 2);
    ushort_t* w2_hi   = (ushort_t*)carve(32768 * 2);
    ushort_t* w2_lo   = (ushort_t*)carve(32768 * 2);
    ushort_t* w3_hi   = (ushort_t*)carve(8192 * 2);
    ushort_t* w3_lo   = (ushort_t*)carve(8192 * 2);
    (void)carve(65536);   // tail pad: unguarded A-loads overrun < 13 KB

    const int NB = (NN + 255) / 256;   // 196
    const int GB = (NN + 63) / 64;     // 782

    // merged prep (hist + convert + all weight prep) then CSR scan + scatter
    hipMemsetAsync(counts, 0, (size_t)NN * 4, stream);
    prep_all<<<HIST_B + CONV_B + WMSG_B + WUPD_B + MLP_B, 256, 0, stream>>>(
        dstp, counts, x, xf,
        W_msg, wmsg_hi, wmsg_lo,
        W_upd, wupd_hi, wupd_lo,
        W1, W2, W3, w1_hi, w1_lo, w2_hi, w2_lo, w3_hi, w3_lo);
    blocksum_kernel<<<NB, 256, 0, stream>>>(counts, bsum);
    scanb_kernel<<<1, 256, 0, stream>>>(bsum, boff, row_start, NB);
    localscan_kernel<<<NB, 256, 0, stream>>>(counts, boff, row_start, cursor);
    scatter_kernel<<<(NE + 255) / 256, 256, 0, stream>>>(srcp, dstp, cursor, colv);

    // m_0 = tanh(x Wm_0^T + bm_0)
    gemm_ldsb<4, 8, 2, true, 2><<<GB, 256, 0, stream>>>(
        xf, wmsg_hi, wmsg_lo, 8, b_msg, m, nullptr, 128, 128);

    // 21 layers; h ping-pongs xf <-> hA
    const ushort_t* cur = xf;
    ushort_t* nxt = hA;
    for (int l = 0; l < 21; ++l){
        aggregate_kernel<<<NN / 4, 256, 0, stream>>>(m, row_start, colv, ag);
        if (l < 20){
            fused_update_msg<true><<<GB, 256, 0, stream>>>(
                ag, cur,
                wupd_hi + (size_t)l * 32768, wupd_lo + (size_t)l * 32768,
                wmsg_hi + (size_t)(l + 1) * 16384, wmsg_lo + (size_t)(l + 1) * 16384,
                b_msg + (size_t)(l + 1) * 128,
                nxt, m);
        } else {
            fused_update_msg<false><<<GB, 256, 0, stream>>>(
                ag, cur,
                wupd_hi + (size_t)l * 32768, wupd_lo + (size_t)l * 32768,
                nullptr, nullptr, nullptr,
                nxt, nullptr);
        }
        const ushort_t* t = cur; cur = nxt; nxt = (ushort_t*)t;
    }
    // after 21 layers: cur == hA; xf, m, ag free

    // MLP head: h1 (N x 256 fp16) overlays m..ag span; h2 = xf
    ushort_t* h1 = m;
    gemm_ldsb<4, 8, 1, true, 2><<<dim3(GB, 2), 256, 0, stream>>>(
        cur, w1_hi, w1_lo, 16, b1, h1, nullptr, 256, 256);
    gemm_ldsb<8, 8, 1, true, 2><<<GB, 256, 0, stream>>>(
        h1, w2_hi, w2_lo, 8, b2, xf, nullptr, 128, 128);
    gemm_ldsb<4, 4, 0, true, 0><<<GB, 256, 0, stream>>>(
        xf, w3_hi, w3_lo, 4, b3, nullptr, (float*)d_out, 63, 63);
}